// Round 15
// baseline (106.339 us; speedup 1.0000x reference)
//
#include <hip/hip_runtime.h>

typedef _Float16 half8  __attribute__((ext_vector_type(8)));
typedef __fp16   fp16x2 __attribute__((ext_vector_type(2)));   // cvt_pkrtz native type
typedef float    floatx4 __attribute__((ext_vector_type(4)));
typedef float    f32x16 __attribute__((ext_vector_type(16)));
typedef float    f4a __attribute__((ext_vector_type(4), aligned(4)));  // 4B-aligned float4 load

#define IMG_H 64
#define IMG_W 64
#define TH 8              // rows per block; full image width
#define INW 72            // staged cols: img cols -4 .. 67 (zeros outside 0..63)
#define H1W 66            // h1 cols 0..65 = img cols -1..64 (cols 0 and 65 always zero)
#define H1H 9             // h1 rows 0..8 = img rows ty0-1 .. ty0+7
#define PLDW (H1H*H1W*2)  // dwords per h1 plane = 1188
#define CP 880            // f16 elems per staged copy; 440 dw ≡ 24 mod 32 banks
#define CPM1 879          // reader: elem off = c*CPM1 + 4 + S + row*INW  (879 ≡ 3 mod 4)
#define S16N (4*CP + 4)   // +4: copy-3 tail spill pad

__device__ __forceinline__ unsigned pk2u(float a, float b) {
    fp16x2 h = __builtin_amdgcn_cvt_pkrtz(a, b);
    return __builtin_bit_cast(unsigned, h);
}

__global__ __launch_bounds__(256, 4) void pixelcnn_mfma19(
    const float* __restrict__ x,
    const float* __restrict__ w1, const float* __restrict__ b1,
    const float* __restrict__ w2, const float* __restrict__ b2,
    const float* __restrict__ w3, const float* __restrict__ b3,
    float* __restrict__ out)
{
    // LDS: 7048 + 2560 + 9504 = 19112 B. DS-DIET (round 15): P2 switched to
    // 32x32x16 fp8 MFMA -- K=16 = 1 tap x 16 ic, B-frag = 8B = one h1 cell
    // (plane = lane>>5 = ic-half). Out-ch o remapped to D-row
    // rho(o) = (o&3)+8*((o>>2)&1)+16*(o>>3): for lanes<32, acc reg r = out-ch r
    // -> w3-dot is LANE-LOCAL (kills all 16 shfl_xor = biggest DS-pipe item).
    __shared__ __align__(16) _Float16      s16[S16N];      // input strip f16, 4 shifted copies
    __shared__ __align__(16) unsigned char s_w2A[32 * 80]; // [row32][tap5][16B ic-fp8] A-frags
    __shared__ __align__(16) unsigned      s_h1[2 * PLDW]; // fp8 h1: [plane][px][8ch] 8B/px/plane

    const int t    = threadIdx.x;
    const int lane = t & 63;
    const int wave = t >> 6;
    const int n    = lane & 15;   // P1 MFMA: weight-row ch field & B-col pixel field
    const int quad = lane >> 4;   // P1 MFMA k-slice group / D-row quad
    const int l31  = lane & 31;   // P2 32x32: D/B col field
    const int hi   = lane >> 5;   // P2 32x32: k-half (= h1 plane)
    const int img  = blockIdx.y;
    const int ty0  = blockIdx.x * TH;

    const float* xim = x + img * (IMG_H * IMG_W);

    // ------- Per-lane weights/biases DIRECT from global (L2-hot, 3KB total) -------
    const float* wr = w1 + n * 49 + quad * 7;
    f4a wlo = *(const f4a*)wr;          // kc 0..3
    f4a whi = *(const f4a*)(wr + 3);    // kc 3..6 (max idx 762 < 784: in-bounds)
    const floatx4 bias1 = *(const floatx4*)(b1 + quad * 4);
    const floatx4 b2q0 = *(const floatx4*)(b2 + 0),  b2q1 = *(const floatx4*)(b2 + 4);
    const floatx4 b2q2 = *(const floatx4*)(b2 + 8),  b2q3 = *(const floatx4*)(b2 + 12);
    const floatx4 w3q0 = *(const floatx4*)(w3 + 0),  w3q1 = *(const floatx4*)(w3 + 4);
    const floatx4 w3q2 = *(const floatx4*)(w3 + 8),  w3q3 = *(const floatx4*)(w3 + 12);
    const float   bias3 = b3[0];
    half8 af;
    {
        bool q3 = (quad == 3);
        af[0] = (_Float16)wlo[0];
        af[1] = (_Float16)wlo[1];
        af[2] = (_Float16)wlo[2];
        af[3] = (_Float16)(q3 ? 0.f : wlo[3]);
        af[4] = (_Float16)(q3 ? 0.f : whi[1]);
        af[5] = (_Float16)(q3 ? 0.f : whi[2]);
        af[6] = (_Float16)(q3 ? 0.f : whi[3]);
        af[7] = (_Float16)0.f;
    }

    // ------- Phase 0 prologue: stage (t<216) + border zero (216-233) + w2A prep (t<160) -------
    if (t < 216) {
        // Copy c stores col X of row r at elem c*CP + 4 + r*INW + (X - c); reader uses
        // E = c*CPM1 + 4 + S + row*INW (E ≡ 0 mod 4 since S ≡ c mod 4). OOB -> zeros.
        int r = t / 18, c4 = (t - r * 18) * 4;
        int gy = ty0 - 4 + r;
        int gx0 = c4 - 4;
        float4 v  = {0.f, 0.f, 0.f, 0.f};
        float4 v2 = {0.f, 0.f, 0.f, 0.f};
        if ((unsigned)gy < IMG_H) {
            const float* rp = xim + gy * IMG_W;
            if ((unsigned)gx0 < IMG_W)       v  = *(const float4*)(rp + gx0);
            if ((unsigned)(gx0 + 4) < IMG_W) v2 = *(const float4*)(rp + gx0 + 4);
        }
        unsigned a0 = pk2u(v.x,  v.y),  a1 = pk2u(v.z,  v.w);
        unsigned a2 = pk2u(v2.x, v2.y), a3 = pk2u(v2.z, v2.w);
        unsigned m10 = __builtin_amdgcn_alignbit(a1, a0, 16);
        unsigned m21 = __builtin_amdgcn_alignbit(a2, a1, 16);
        unsigned m32 = __builtin_amdgcn_alignbit(a3, a2, 16);
        int lin = r * INW + c4;
        *(uint2*)&s16[0*CP + 4 + lin] = uint2{a0,  a1 };
        *(uint2*)&s16[1*CP + 4 + lin] = uint2{m10, m21};
        *(uint2*)&s16[2*CP + 4 + lin] = uint2{a1,  a2 };
        *(uint2*)&s16[3*CP + 4 + lin] = uint2{m21, m32};
    } else if (t < 234) {
        // zero h1 border cols 0 and 65 (always out of image). 9 rows x {0,65}.
        int idx = t - 216;
        int cell = (idx >> 1) * H1W + ((idx & 1) ? 65 : 0);
        *(uint2*)&s_h1[cell * 2]        = uint2{0u, 0u};
        *(uint2*)&s_h1[PLDW + cell * 2] = uint2{0u, 0u};
    }
    if (t < 160) {
        // w2A: A-fragments for 32x32x16 fp8. row in [0,32), tap in [0,5).
        // Row rho(o) holds w2[o][tap][ic0..15] as 16 fp8 bytes; rows with bit2=1 -> 0.
        int row = (t * 205) >> 10;       // t/5 (exact for t<160)
        int tap = t - row * 5;
        uint4 w4 = {0u, 0u, 0u, 0u};
        if (!(row & 4)) {
            int o = (row & 3) | ((row & 24) >> 1);     // inverse of rho
            const float* wp = w2 + (o * 16) * 9 + tap; // [o][ic][tap], ic stride 9
            unsigned d0 = (unsigned)__builtin_amdgcn_cvt_pk_fp8_f32(wp[0],   wp[9],   0,  false);
            d0          = (unsigned)__builtin_amdgcn_cvt_pk_fp8_f32(wp[18],  wp[27],  d0, true);
            unsigned d1 = (unsigned)__builtin_amdgcn_cvt_pk_fp8_f32(wp[36],  wp[45],  0,  false);
            d1          = (unsigned)__builtin_amdgcn_cvt_pk_fp8_f32(wp[54],  wp[63],  d1, true);
            unsigned d2 = (unsigned)__builtin_amdgcn_cvt_pk_fp8_f32(wp[72],  wp[81],  0,  false);
            d2          = (unsigned)__builtin_amdgcn_cvt_pk_fp8_f32(wp[90],  wp[99],  d2, true);
            unsigned d3 = (unsigned)__builtin_amdgcn_cvt_pk_fp8_f32(wp[108], wp[117], 0,  false);
            d3          = (unsigned)__builtin_amdgcn_cvt_pk_fp8_f32(wp[126], wp[135], d3, true);
            w4 = uint4{d0, d1, d2, d3};
        }
        *(uint4*)&s_w2A[row * 80 + tap * 16] = w4;
    }
    __syncthreads();

    // ------- Phase 1: L1 7x7 via f16 MFMA (UNCHANGED, proven) -------
    {
        const int px = wave * 16 + n;
        const int S  = px + 1;
        const int c  = S & 3;
        const _Float16* ap0 = &s16[c * CPM1 + 4 + S + quad * INW];
        const unsigned wd0 = (unsigned)((quad >> 1) * PLDW + S * 2 + (quad & 1));
        const bool top = (ty0 == 0);

#pragma unroll
        for (int i = 0; i < H1H; ++i) {
            const _Float16* ap = ap0 + i * INW;
            uint2 lo = *(const uint2*)ap;
            uint2 hi2 = *(const uint2*)(ap + 4);
            uint4 bu; bu.x = lo.x; bu.y = lo.y; bu.z = hi2.x; bu.w = hi2.y;
            half8 b = __builtin_bit_cast(half8, bu);
            floatx4 acc = bias1;
            acc = __builtin_amdgcn_mfma_f32_16x16x32_f16(af, b, acc, 0, 0, 0);
            int d = __builtin_amdgcn_cvt_pk_fp8_f32(fmaxf(acc[0], 0.f), fmaxf(acc[1], 0.f), 0, false);
            d = __builtin_amdgcn_cvt_pk_fp8_f32(fmaxf(acc[2], 0.f), fmaxf(acc[3], 0.f), d, true);
            unsigned dv = (unsigned)d;
            if (i == 0 && top) dv = 0u;
            s_h1[wd0 + i * (H1W * 2)] = dv;
        }
    }
    __syncthreads();

    // ------- Phase 2: L2 3x3 via fp8 32x32x16 MFMA, lane-local w3-dot -------
    // Wave (colhalf = wave&1, yhalf = wave>>1) covers 32 px x 4 out rows.
    // Per out row: 5 MFMAs (taps (-1,-1),(-1,0),(-1,1),(0,-1),(0,0)), each B-frag
    // = 8B h1 cell at [plane=hi][row y+1+dy][col colhalf*32+l31+1+dx].
    {
        const char* wab = (const char*)s_w2A + l31 * 80 + hi * 8;
        const long wA0 = *(const long*)(wab +  0);
        const long wA1 = *(const long*)(wab + 16);
        const long wA2 = *(const long*)(wab + 32);
        const long wA3 = *(const long*)(wab + 48);
        const long wA4 = *(const long*)(wab + 64);
        const int colhalf = wave & 1, yhalf = wave >> 1;
        const char* hb = (const char*)s_h1 + hi * (PLDW * 4);
        const char* bb = hb + ((yhalf * 4) * H1W + colhalf * 32 + l31 + 1) * 8;
        // C init = b2 in rho-order: lane<32 reg r = b2[r]; lanes>=32 harmless (masked store)
        f32x16 biasC;
        biasC[0]=b2q0[0]; biasC[1]=b2q0[1]; biasC[2]=b2q0[2]; biasC[3]=b2q0[3];
        biasC[4]=b2q1[0]; biasC[5]=b2q1[1]; biasC[6]=b2q1[2]; biasC[7]=b2q1[3];
        biasC[8]=b2q2[0]; biasC[9]=b2q2[1]; biasC[10]=b2q2[2]; biasC[11]=b2q2[3];
        biasC[12]=b2q3[0]; biasC[13]=b2q3[1]; biasC[14]=b2q3[2]; biasC[15]=b2q3[3];
        float* sbase = out + ((img * IMG_H) + ty0 + yhalf * 4) * IMG_W + colhalf * 32 + l31;

#pragma unroll
        for (int j = 0; j < 4; ++j) {              // out row = ty0 + yhalf*4 + j
            f32x16 acc = biasC;
            acc = __builtin_amdgcn_mfma_f32_32x32x16_fp8_fp8(wA0, *(const long*)(bb + (j * 66 - 1) * 8), acc, 0, 0, 0);
            acc = __builtin_amdgcn_mfma_f32_32x32x16_fp8_fp8(wA1, *(const long*)(bb + (j * 66    ) * 8), acc, 0, 0, 0);
            acc = __builtin_amdgcn_mfma_f32_32x32x16_fp8_fp8(wA2, *(const long*)(bb + (j * 66 + 1) * 8), acc, 0, 0, 0);
            acc = __builtin_amdgcn_mfma_f32_32x32x16_fp8_fp8(wA3, *(const long*)(bb + ((j + 1) * 66 - 1) * 8), acc, 0, 0, 0);
            acc = __builtin_amdgcn_mfma_f32_32x32x16_fp8_fp8(wA4, *(const long*)(bb + ((j + 1) * 66    ) * 8), acc, 0, 0, 0);
            // lane-local relu + w3 dot over 16 out-ch (reg r = ch r for lane<32)
            float s;
            s = fmaxf(acc[0],  0.f) * w3q0[0];
            s = fmaf(fmaxf(acc[1],  0.f), w3q0[1], s);
            s = fmaf(fmaxf(acc[2],  0.f), w3q0[2], s);
            s = fmaf(fmaxf(acc[3],  0.f), w3q0[3], s);
            s = fmaf(fmaxf(acc[4],  0.f), w3q1[0], s);
            s = fmaf(fmaxf(acc[5],  0.f), w3q1[1], s);
            s = fmaf(fmaxf(acc[6],  0.f), w3q1[2], s);
            s = fmaf(fmaxf(acc[7],  0.f), w3q1[3], s);
            s = fmaf(fmaxf(acc[8],  0.f), w3q2[0], s);
            s = fmaf(fmaxf(acc[9],  0.f), w3q2[1], s);
            s = fmaf(fmaxf(acc[10], 0.f), w3q2[2], s);
            s = fmaf(fmaxf(acc[11], 0.f), w3q2[3], s);
            s = fmaf(fmaxf(acc[12], 0.f), w3q3[0], s);
            s = fmaf(fmaxf(acc[13], 0.f), w3q3[1], s);
            s = fmaf(fmaxf(acc[14], 0.f), w3q3[2], s);
            s = fmaf(fmaxf(acc[15], 0.f), w3q3[3], s);
            float r = __builtin_amdgcn_rcpf(1.f + __expf(-(s + bias3)));
            if (lane < 32) *(float*)((char*)sbase + j * 256) = r;
        }
    }
}

extern "C" void kernel_launch(void* const* d_in, const int* in_sizes, int n_in,
                              void* d_out, int out_size, void* d_ws, size_t ws_size,
                              hipStream_t stream) {
    const float* x  = (const float*)d_in[0];
    const float* w1 = (const float*)d_in[1];
    const float* b1 = (const float*)d_in[2];
    const float* w2 = (const float*)d_in[3];
    const float* b2 = (const float*)d_in[4];
    const float* w3 = (const float*)d_in[5];
    const float* b3 = (const float*)d_in[6];
    float* out = (float*)d_out;

    dim3 grid(8, 1024);   // 8 row-strips per image, 1024 images
    dim3 block(256);
    hipLaunchKernelGGL(pixelcnn_mfma19, grid, block, 0, stream,
                       x, w1, b1, w2, b2, w3, b3, out);
}

// Round 16
// 100.837 us; speedup vs baseline: 1.0546x; 1.0546x over previous
//
#include <hip/hip_runtime.h>

typedef _Float16 half8  __attribute__((ext_vector_type(8)));
typedef __fp16   fp16x2 __attribute__((ext_vector_type(2)));   // cvt_pkrtz native type
typedef float    floatx4 __attribute__((ext_vector_type(4)));
typedef float    f4a __attribute__((ext_vector_type(4), aligned(4)));  // 4B-aligned float4 load

#define IMG_H 64
#define IMG_W 64
#define TH 16             // rows per block (two 8-row strips); full image width
#define INW 72            // staged cols: img cols -4 .. 67 (zeros outside 0..63)
#define H1W 66            // h1 cols 0..65 = img cols -1..64 (cols 0 and 65 always zero)
#define H1H 17            // h1 rows 0..16 = img rows ty0-1 .. ty0+15
#define PLDW (H1H*H1W*2)  // dwords per h1 plane = 2244
#define CP 1440           // f16 elems per staged copy (20 rows x 72)
#define CPM1 1439         // reader: elem off = c*CPM1 + 4 + S + row*INW
#define S16N (4*CP + 4)   // +4: copy-3 tail spill pad

__device__ __forceinline__ unsigned pk2u(float a, float b) {
    fp16x2 h = __builtin_amdgcn_cvt_pkrtz(a, b);
    return __builtin_bit_cast(unsigned, h);
}

__global__ __launch_bounds__(512, 8) void pixelcnn_mfma20(
    const float* __restrict__ x,
    const float* __restrict__ w1, const float* __restrict__ b1,
    const float* __restrict__ w2, const float* __restrict__ b2,
    const float* __restrict__ w3, const float* __restrict__ b3,
    float* __restrict__ out)
{
    // LDS: 11528 + 1536 + 17952 = 31016 B -> 4 blocks/CU x 8 waves = 32 waves/CU (full)
    // Round 16: mfma12 (proven 101.24) + butterfly reduce-to-owner in P2:
    // 3 shuffles per 4-row group (2x xor16 swizzle + 1x xor32 bpermute) instead of 8
    // (4 swizzle + 4 two-pass bpermute). Same (q0+q1)+(q2+q3) association ->
    // bit-identical output. Tests DS-pipe/bpermute cost at UNCHANGED occupancy.
    __shared__ __align__(16) _Float16      s16[S16N];      // input strip f16, 4 shifted copies
    __shared__ __align__(16) unsigned char s_w2t8[16 * 96];// [ch][k] fp8 e4m3, k=tap*16+ic
    __shared__ __align__(16) unsigned      s_h1[2 * PLDW]; // fp8 h1: [plane][px][8ch] 8B/px/plane

    const int t    = threadIdx.x;
    const int lane = t & 63;
    const int wave = t >> 6;
    const int n    = lane & 15;   // MFMA: weight-row ch field & B-col pixel field
    const int quad = lane >> 4;   // MFMA k-slice group / D-row quad
    const int s    = wave >> 2;   // strip (0: rows ty0..+7, 1: rows ty0+8..+15)
    const int x0q  = wave & 3;    // col quarter
    const int img  = blockIdx.y;
    const int ty0  = blockIdx.x * TH;

    const float* xim = x + img * (IMG_H * IMG_W);

    // ------- Per-lane weights/biases DIRECT from global (L2-hot, 3KB total) -------
    // A-frag: w1[n][kr=quad][kc=j], j<7 (quad<3) / j<3 (quad==3); RTE casts match old path.
    const float* wr = w1 + n * 49 + quad * 7;
    f4a wlo = *(const f4a*)wr;          // kc 0..3   (4B-aligned load)
    f4a whi = *(const f4a*)(wr + 3);    // kc 3..6   (max idx 762 < 784: in-bounds)
    const floatx4 bias1 = *(const floatx4*)(b1 + quad * 4);
    const floatx4 bias2 = *(const floatx4*)(b2 + quad * 4);
    const floatx4 w3q   = *(const floatx4*)(w3 + quad * 4);
    const float   bias3 = b3[0];
    half8 af;
    {
        bool q3 = (quad == 3);
        af[0] = (_Float16)wlo[0];
        af[1] = (_Float16)wlo[1];
        af[2] = (_Float16)wlo[2];
        af[3] = (_Float16)(q3 ? 0.f : wlo[3]);
        af[4] = (_Float16)(q3 ? 0.f : whi[1]);
        af[5] = (_Float16)(q3 ? 0.f : whi[2]);
        af[6] = (_Float16)(q3 ? 0.f : whi[3]);
        af[7] = (_Float16)0.f;
    }

    // ------- Phase 0: stage 20-row input strip as f16 x4 shifted copies -------
    // Copy c stores col X of row r at elem c*CP + 4 + r*INW + (X - c); reader uses
    // E = c*CPM1 + 4 + S + row*INW (E ≡ 0 mod 4 since S ≡ c mod 4). OOB loads -> zeros.
    if (t < 360) {
        int r = t / 18, c4 = (t - r * 18) * 4;
        int gy = ty0 - 4 + r;
        int gx0 = c4 - 4;                       // img col, multiple of 4
        float4 v  = {0.f, 0.f, 0.f, 0.f};
        float4 v2 = {0.f, 0.f, 0.f, 0.f};
        if ((unsigned)gy < IMG_H) {
            const float* rp = xim + gy * IMG_W;
            if ((unsigned)gx0 < IMG_W)       v  = *(const float4*)(rp + gx0);
            if ((unsigned)(gx0 + 4) < IMG_W) v2 = *(const float4*)(rp + gx0 + 4);
        }
        unsigned a0 = pk2u(v.x,  v.y),  a1 = pk2u(v.z,  v.w);
        unsigned a2 = pk2u(v2.x, v2.y), a3 = pk2u(v2.z, v2.w);
        unsigned m10 = __builtin_amdgcn_alignbit(a1, a0, 16);   // elems 1,2
        unsigned m21 = __builtin_amdgcn_alignbit(a2, a1, 16);   // elems 3,4
        unsigned m32 = __builtin_amdgcn_alignbit(a3, a2, 16);   // elems 5,6
        int lin = r * INW + c4;
        *(uint2*)&s16[0*CP + 4 + lin] = uint2{a0,  a1 };  // cols c4..c4+3
        *(uint2*)&s16[1*CP + 4 + lin] = uint2{m10, m21};  // cols c4+1..c4+4
        *(uint2*)&s16[2*CP + 4 + lin] = uint2{a1,  a2 };  // cols c4+2..c4+5
        *(uint2*)&s16[3*CP + 4 + lin] = uint2{m21, m32};  // cols c4+3..c4+6
    } else if (t < 394) {
        // zero h1 border cols 0 and 65 (img cols -1, 64 -> always out of image);
        // phase 1 never writes these cells, phase 2 reads them. 17 rows x {0,65}.
        int idx = t - 360;
        int cell = (idx >> 1) * H1W + ((idx & 1) ? 65 : 0);
        *(uint2*)&s_h1[cell * 2]        = uint2{0u, 0u};
        *(uint2*)&s_h1[PLDW + cell * 2] = uint2{0u, 0u};
    }
    if (t >= 256) {
        // w2t8: k = tap*16 + ic, fp8 e4m3 -- 256 threads = 16 ch x 16 ic
        int ch = (t >> 4) & 15, l = t & 15;
        const float* w2cl = w2 + (ch * 16 + l) * 9;
#pragma unroll
        for (int j = 0; j < 6; ++j) {
            float v = (j < 5) ? w2cl[j] : 0.f;
            unsigned q8 = (unsigned)__builtin_amdgcn_cvt_pk_fp8_f32(v, 0.f, 0, false);
            s_w2t8[ch * 96 + j * 16 + l] = (unsigned char)(q8 & 0xff);
        }
    }
    __syncthreads();

    // ------- Phase 1: L1 7x7 via f16 MFMA; fixed column per lane, rows advance -------
    // Wave (s, x0q): h1 rows s*8 .. s*8+8. Strip 1 skips i=0 (row 8 owned by strip 0).
    {
        const int px = x0q * 16 + n;              // img col, 0..63
        const int S  = px + 1;                    // staged read start col
        const int c  = S & 3;                     // copy index: fixed per lane
        const _Float16* ap0 = &s16[c * CPM1 + 4 + S + (s * 8 + quad) * INW];
        const unsigned wd0 = (unsigned)((quad >> 1) * PLDW + ((s * 8) * H1W + S) * 2 + (quad & 1));
        const bool top = (ty0 == 0) && (s == 0);

#pragma unroll
        for (int i = 0; i < 9; ++i) {             // h1 row s*8+i = img row ty0-1+s*8+i
            if (i == 0 && s != 0) continue;       // row 8 owned by strip 0
            const _Float16* ap = ap0 + i * INW;
            uint2 lo = *(const uint2*)ap;         // staged cols S..S+3 (8B aligned)
            uint2 hi = *(const uint2*)(ap + 4);   // staged cols S+4..S+7
            uint4 bu; bu.x = lo.x; bu.y = lo.y; bu.z = hi.x; bu.w = hi.y;
            half8 b = __builtin_bit_cast(half8, bu);
            floatx4 acc = bias1;
            acc = __builtin_amdgcn_mfma_f32_16x16x32_f16(af, b, acc, 0, 0, 0);
            // D: row = ch = quad*4+r, col = px = n -> 4 ch as 4 fp8 bytes = one b32
            int d = __builtin_amdgcn_cvt_pk_fp8_f32(fmaxf(acc[0], 0.f), fmaxf(acc[1], 0.f), 0, false);
            d = __builtin_amdgcn_cvt_pk_fp8_f32(fmaxf(acc[2], 0.f), fmaxf(acc[3], 0.f), d, true);
            unsigned dv = (unsigned)d;
            if (i == 0 && top) dv = 0u;           // h1 row 0 = img row -1 for top block
            s_h1[wd0 + i * (H1W * 2)] = dv;
        }
    }
    __syncthreads();

    // ------- Phase 2: L2 3x3 via fp8 MFMA + fused relu/w3-dot/sigmoid/store -------
    {
        const long w2f0 = *(const long*)&s_w2t8[n * 96 +  0 + quad * 8];
        const long w2f1 = *(const long*)&s_w2t8[n * 96 + 32 + quad * 8];
        const long w2f2 = *(const long*)&s_w2t8[n * 96 + 64 + quad * 8];
        const int x0 = x0q * 16;
        const int tqh = quad >> 1, plane = quad & 1;
        const int E0 = (s * 8 + 1) * H1W + x0 + n + 1;   // lane pixel, out row ty0+s*8 (k=0)
        // taps: f0 -> {(-1,-1),(-1,0)}, f1 -> {(-1,1),(0,-1)}, f2 -> {(0,0), pad(A=0)}
        const char* h1b = (const char*)s_h1 + plane * (PLDW * 4);
        const char* a0 = h1b + (E0 - H1W - 1 + tqh) * 8;
        const char* a1 = h1b + (E0 + (tqh ? -1 : -(H1W - 1))) * 8;
        const char* a2 = h1b + E0 * 8;                   // tqh=1 reads real px (zero A-side)
        // lane (n, quad) stores row ty0 + s*8 + g*4 + quad, col x0 + n
        float* sbase = out + ((img * IMG_H) + ty0 + s * 8 + quad) * IMG_W + x0 + n;

#pragma unroll
        for (int g = 0; g < 2; ++g) {                    // 2 groups of 4 rows
            float p0, p1, p2, p3;                        // lane's 4-ch partials, rows g*4+0..3
#pragma unroll
            for (int q = 0; q < 4; ++q) {                // k = g*4+q; row step = 66 px = 528 B
                const int k = g * 4 + q;
                floatx4 acc = bias2;
                acc = __builtin_amdgcn_mfma_f32_16x16x32_fp8_fp8(w2f0, *(const long*)(a0 + k * 528), acc, 0, 0, 0);
                acc = __builtin_amdgcn_mfma_f32_16x16x32_fp8_fp8(w2f1, *(const long*)(a1 + k * 528), acc, 0, 0, 0);
                acc = __builtin_amdgcn_mfma_f32_16x16x32_fp8_fp8(w2f2, *(const long*)(a2 + k * 528), acc, 0, 0, 0);
                float sacc = fmaxf(acc[0], 0.f) * w3q[0];
                sacc = fmaf(fmaxf(acc[1], 0.f), w3q[1], sacc);
                sacc = fmaf(fmaxf(acc[2], 0.f), w3q[2], sacc);
                sacc = fmaf(fmaxf(acc[3], 0.f), w3q[3], sacc);
                if      (q == 0) p0 = sacc;
                else if (q == 1) p1 = sacc;
                else if (q == 2) p2 = sacc;
                else             p3 = sacc;
            }
            // Butterfly reduce-to-owner: lane (n,quad) needs row g*4+quad's total =
            // sum of p[quad] over the 4 quad-groups. Step1 (xor16, partner quad^1):
            // exchange p[quad^1] and p[quad^3] -> pair-sums A (row quad), B (row quad^2).
            // Step2 (xor32, partner quad^2): exchange B -> T = A + partner.B.
            // Association (q0+q1)+(q2+q3) identical to old 8-shuffle form -> bit-identical.
            float t01a = (quad & 1) ? p1 : p0;           // p[bit0]
            float t01b = (quad & 1) ? p0 : p1;           // p[!bit0]
            float t23a = (quad & 1) ? p3 : p2;           // p[2+bit0]
            float t23b = (quad & 1) ? p2 : p3;           // p[2+!bit0]
            float pq   = (quad & 2) ? t23a : t01a;       // p[quad]
            float s1   = (quad & 2) ? t23b : t01b;       // p[quad^1]
            float px2  = (quad & 2) ? t01a : t23a;       // p[quad^2]
            float s2   = (quad & 2) ? t01b : t23b;       // p[quad^3]
            float A = pq  + __shfl_xor(s1, 16);          // pair {quad,quad^1}, row quad
            float B = px2 + __shfl_xor(s2, 16);          // pair {quad,quad^1}, row quad^2
            float T = A  + __shfl_xor(B, 32);            // + other pair's row quad
            float r = __builtin_amdgcn_rcpf(1.f + __expf(-(T + bias3)));
            *(float*)((char*)sbase + g * 1024) = r;      // +4 rows per group
        }
    }
}

extern "C" void kernel_launch(void* const* d_in, const int* in_sizes, int n_in,
                              void* d_out, int out_size, void* d_ws, size_t ws_size,
                              hipStream_t stream) {
    const float* x  = (const float*)d_in[0];
    const float* w1 = (const float*)d_in[1];
    const float* b1 = (const float*)d_in[2];
    const float* w2 = (const float*)d_in[3];
    const float* b2 = (const float*)d_in[4];
    const float* w3 = (const float*)d_in[5];
    const float* b3 = (const float*)d_in[6];
    float* out = (float*)d_out;

    dim3 grid(4, 1024);   // 4 16-row strips per image, 1024 images
    dim3 block(512);
    hipLaunchKernelGGL(pixelcnn_mfma20, grid, block, 0, stream,
                       x, w1, b1, w2, b2, w3, b3, out);
}